// Round 1
// baseline (399.937 us; speedup 1.0000x reference)
//
#include <hip/hip_runtime.h>
#include <stdint.h>

// Deep-TEN encoding, fused one-pass kernel.
// B=64, N=4096, D=256, K=32.
// Per block: one (batch, 256-row chunk); loop over 8 tiles of 32 rows.
//   phase A: xc[n][k] via mfma_f32_16x16x32_bf16 (A = x row-major from LDS,
//            B = C fragments preloaded in registers)
//   softmax over K=32 in C/D register layout (16-lane butterflies + one
//            cross-k-tile exchange through LDS)
//   phase B: E[k][d] += w^T[k][n] * x[n][d] via mfma (A = w from LDS "wt",
//            B = x transposed bf16 "xt"), accumulated in registers.
// Epilogue: E -= (sum_n w) * C, then unsafeAtomicAdd into d_out (zeroed by
// hipMemsetAsync; 16 blocks/batch contribute).

#define NN 4096
#define DD 256
#define KK 32

typedef __attribute__((ext_vector_type(8))) short short8;   // 8 x bf16
typedef __attribute__((ext_vector_type(4))) float float4v;  // mfma acc

__device__ __forceinline__ unsigned short f2bf(float f) {
    unsigned u = __float_as_uint(f);
    unsigned r = (u + 0x7fffu + ((u >> 16) & 1u)) >> 16;   // RNE
    return (unsigned short)r;
}
__device__ __forceinline__ unsigned pk2(float a, float b) {
    return (unsigned)f2bf(a) | ((unsigned)f2bf(b) << 16);
}
__device__ __forceinline__ short8 pack8(float4 a, float4 b) {
    short8 r;
    r[0] = (short)f2bf(a.x); r[1] = (short)f2bf(a.y);
    r[2] = (short)f2bf(a.z); r[3] = (short)f2bf(a.w);
    r[4] = (short)f2bf(b.x); r[5] = (short)f2bf(b.y);
    r[6] = (short)f2bf(b.z); r[7] = (short)f2bf(b.w);
    return r;
}

__launch_bounds__(256)
__global__ void dten_kernel(const float* __restrict__ X,
                            const float* __restrict__ Cg,
                            const float* __restrict__ Sg,
                            float* __restrict__ out) {
    const int b     = blockIdx.y;
    const int chunk = blockIdx.x;          // 0..15, 256 rows each
    const int tid   = threadIdx.x;
    const int lane  = tid & 63;
    const int wv    = tid >> 6;            // wave 0..3
    const int lk    = lane & 15;
    const int lq    = lane >> 4;           // 0..3
    // staging mapping: 2 rows x 16 floats per thread
    const int rp = tid & 15;               // row-pair 0..15 (rows 2rp, 2rp+1)
    const int dc = tid >> 4;               // d-chunk 0..15 (16 floats)
    // phase A wave roles
    const int nt = wv >> 1;                // n-subtile (16 rows)
    const int kt = wv & 1;                 // k-tile (16 k's)

    // LDS. pitches padded for bank-floor access (no swizzles needed):
    // xa: row-major bf16 x tile [32][256], pitch 264 ushorts (528 B)
    // xt: col-major bf16 x tile [256][32], pitch 40 ushorts (80 B)
    // wt: w^T bf16 [32][32], pitch 40 ushorts
    __shared__ __align__(16) unsigned short xa[32 * 264];
    __shared__ __align__(16) unsigned short xt[256 * 40];
    __shared__ __align__(16) unsigned short wt[32 * 40];
    __shared__ __align__(16) float x2p[4][32];
    __shared__ __align__(16) float mex[2][32];
    __shared__ __align__(16) float sex[2][32];
    __shared__ __align__(16) float wsum_p[2][32];

    // ---- preload C fragments (mfma B-operand) for this wave's k-tile ----
    // B-frag: lane holds B[kc=(lane>>4)*8+j][n=lane&15] = C[k0+lk][d0+lq*8+j]
    const int kA = kt * 16 + lk;           // this lane's k in phase A
    short8 cfrag[8];
    float c2k;
    {
        const float* crow = Cg + (size_t)kA * DD;
        float c2part = 0.f;
        #pragma unroll
        for (int ch = 0; ch < 8; ++ch) {
            float4 u0 = *(const float4*)(crow + ch * 32 + lq * 8);
            float4 u1 = *(const float4*)(crow + ch * 32 + lq * 8 + 4);
            cfrag[ch] = pack8(u0, u1);
            c2part += u0.x*u0.x + u0.y*u0.y + u0.z*u0.z + u0.w*u0.w
                    + u1.x*u1.x + u1.y*u1.y + u1.z*u1.z + u1.w*u1.w;
        }
        c2part += __shfl_xor(c2part, 16);
        c2part += __shfl_xor(c2part, 32);
        c2k = c2part;
    }
    const float sk = Sg[kA];

    float4v eacc[2][4];
    #pragma unroll
    for (int i = 0; i < 2; ++i)
        #pragma unroll
        for (int j = 0; j < 4; ++j)
            eacc[i][j] = (float4v){0.f, 0.f, 0.f, 0.f};
    float wsum_reg = 0.f;

    const int row_base = chunk * 256;
    const int n0 = nt * 16;
    const int nl = n0 + lk;

    for (int t = 0; t < 8; ++t) {
        const int row0 = row_base + t * 32;
        __syncthreads();   // previous tile's phase-B readers done

        // ---------------- stage: global -> xa, xt, x2p ----------------
        const size_t xoff = ((size_t)b * NN + row0 + 2 * rp) * DD + dc * 16;
        const float4* xr0 = (const float4*)(X + xoff);
        const float4* xr1 = (const float4*)(X + xoff + DD);
        float4 v0[4], v1[4];
        #pragma unroll
        for (int i = 0; i < 4; ++i) { v0[i] = xr0[i]; v1[i] = xr1[i]; }

        float s0 = 0.f, s1 = 0.f;
        #pragma unroll
        for (int i = 0; i < 4; ++i) {
            s0 += v0[i].x*v0[i].x + v0[i].y*v0[i].y + v0[i].z*v0[i].z + v0[i].w*v0[i].w;
            s1 += v1[i].x*v1[i].x + v1[i].y*v1[i].y + v1[i].z*v1[i].z + v1[i].w*v1[i].w;
        }
        s0 += __shfl_xor(s0, 16); s0 += __shfl_xor(s0, 32);  // reduce over dc&3
        s1 += __shfl_xor(s1, 16); s1 += __shfl_xor(s1, 32);
        if (lane < 16) { x2p[wv][2 * rp] = s0; x2p[wv][2 * rp + 1] = s1; }

        {
            const int na = 2 * rp, nb = 2 * rp + 1;
            *(short8*)&xa[na * 264 + dc * 16    ] = pack8(v0[0], v0[1]);
            *(short8*)&xa[na * 264 + dc * 16 + 8] = pack8(v0[2], v0[3]);
            *(short8*)&xa[nb * 264 + dc * 16    ] = pack8(v1[0], v1[1]);
            *(short8*)&xa[nb * 264 + dc * 16 + 8] = pack8(v1[2], v1[3]);
        }
        {
            const float* f0 = (const float*)v0;
            const float* f1 = (const float*)v1;
            #pragma unroll
            for (int m = 0; m < 16; ++m) {
                int d = dc * 16 + m;
                *(unsigned*)&xt[d * 40 + 2 * rp] = pk2(f0[m], f1[m]);
            }
        }
        __syncthreads();

        // ---------------- phase A: xc = x . C^T (16n x 16k per wave) ----
        float4v acc = (float4v){0.f, 0.f, 0.f, 0.f};
        #pragma unroll
        for (int ch = 0; ch < 8; ++ch) {
            short8 af = *(const short8*)&xa[nl * 264 + ch * 32 + lq * 8];
            acc = __builtin_amdgcn_mfma_f32_16x16x32_bf16(af, cfrag[ch], acc, 0, 0, 0);
        }
        // lane holds xc[n0+lq*4+r][kA], r=0..3
        float4 xs0 = *(const float4*)&x2p[0][n0 + lq * 4];
        float4 xs1 = *(const float4*)&x2p[1][n0 + lq * 4];
        float4 xs2 = *(const float4*)&x2p[2][n0 + lq * 4];
        float4 xs3 = *(const float4*)&x2p[3][n0 + lq * 4];
        float xsum[4] = { xs0.x + xs1.x + xs2.x + xs3.x,
                          xs0.y + xs1.y + xs2.y + xs3.y,
                          xs0.z + xs1.z + xs2.z + xs3.z,
                          xs0.w + xs1.w + xs2.w + xs3.w };
        float a[4], ml[4];
        #pragma unroll
        for (int r = 0; r < 4; ++r) {
            a[r] = sk * (2.f * acc[r] - xsum[r] - c2k);   // = -S*dist
            ml[r] = a[r];
        }
        #pragma unroll
        for (int mask = 1; mask <= 8; mask <<= 1)
            #pragma unroll
            for (int r = 0; r < 4; ++r)
                ml[r] = fmaxf(ml[r], __shfl_xor(ml[r], mask));
        float e[4], sl[4];
        #pragma unroll
        for (int r = 0; r < 4; ++r) { e[r] = __expf(a[r] - ml[r]); sl[r] = e[r]; }
        #pragma unroll
        for (int mask = 1; mask <= 8; mask <<= 1)
            #pragma unroll
            for (int r = 0; r < 4; ++r)
                sl[r] += __shfl_xor(sl[r], mask);
        if (lk == 0) {
            *(float4*)&mex[kt][n0 + lq * 4] = make_float4(ml[0], ml[1], ml[2], ml[3]);
            *(float4*)&sex[kt][n0 + lq * 4] = make_float4(sl[0], sl[1], sl[2], sl[3]);
        }
        __syncthreads();
        float4 mo4 = *(const float4*)&mex[1 - kt][n0 + lq * 4];
        float4 so4 = *(const float4*)&sex[1 - kt][n0 + lq * 4];
        float mo[4] = { mo4.x, mo4.y, mo4.z, mo4.w };
        float so[4] = { so4.x, so4.y, so4.z, so4.w };
        float w[4];
        #pragma unroll
        for (int r = 0; r < 4; ++r) {
            float M   = fmaxf(ml[r], mo[r]);
            float sc  = __expf(ml[r] - M);
            float den = sl[r] * sc + so[r] * __expf(mo[r] - M);
            w[r] = e[r] * sc / den;
        }
        float ws = w[0] + w[1] + w[2] + w[3];
        ws += __shfl_xor(ws, 16); ws += __shfl_xor(ws, 32);
        wsum_reg += ws;
        // wt[k][n]: 4 consecutive n (= regs) packed as b64
        *(uint2*)&wt[kA * 40 + n0 + lq * 4] = make_uint2(pk2(w[0], w[1]), pk2(w[2], w[3]));
        __syncthreads();

        // ---------------- phase B: E[k][d] += w^T . x ----------------
        // A-frag: wt[k0+lk][lq*8+j]; B-frag: xt[d][lq*8+j]
        short8 af0 = *(const short8*)&wt[lk * 40 + lq * 8];
        short8 af1 = *(const short8*)&wt[(16 + lk) * 40 + lq * 8];
        #pragma unroll
        for (int dt = 0; dt < 4; ++dt) {
            int d = wv * 64 + dt * 16 + lk;
            short8 bf = *(const short8*)&xt[d * 40 + lq * 8];
            eacc[0][dt] = __builtin_amdgcn_mfma_f32_16x16x32_bf16(af0, bf, eacc[0][dt], 0, 0, 0);
            eacc[1][dt] = __builtin_amdgcn_mfma_f32_16x16x32_bf16(af1, bf, eacc[1][dt], 0, 0, 0);
        }
    }

    // ---------------- epilogue: E -= (sum w) * C, atomic to out ----------
    if (lq == 0) wsum_p[nt][kA] = wsum_reg;
    __syncthreads();
    #pragma unroll
    for (int kt2 = 0; kt2 < 2; ++kt2) {
        #pragma unroll
        for (int r = 0; r < 4; ++r) {
            int k = kt2 * 16 + lq * 4 + r;
            float wsk = wsum_p[0][k] + wsum_p[1][k];
            #pragma unroll
            for (int dt = 0; dt < 4; ++dt) {
                int d = wv * 64 + dt * 16 + lk;
                float cv = Cg[k * DD + d];
                float val = eacc[kt2][dt][r] - wsk * cv;
                unsafeAtomicAdd(&out[((size_t)b * KK + k) * DD + d], val);
            }
        }
    }
}

extern "C" void kernel_launch(void* const* d_in, const int* in_sizes, int n_in,
                              void* d_out, int out_size, void* d_ws, size_t ws_size,
                              hipStream_t stream) {
    const float* X = (const float*)d_in[0];
    const float* C = (const float*)d_in[1];
    const float* S = (const float*)d_in[2];
    float* out = (float*)d_out;
    hipMemsetAsync(out, 0, (size_t)out_size * sizeof(float), stream);
    dim3 grid(16, 64);   // 16 row-chunks x 64 batches = 1024 blocks
    dten_kernel<<<grid, dim3(256), 0, stream>>>(X, C, S, out);
}